// Round 3
// baseline (1363.578 us; speedup 1.0000x reference)
//
#include <hip/hip_runtime.h>
#include <hip/hip_cooperative_groups.h>

namespace cg = cooperative_groups;

#define F_IN 512
#define HID 16
#define NCLS 64
#define NBUCK_MAX 512     // LDS sizing; actual nbuck = ceil(N/256) = 391
#define EPB 8192          // edges per block in the hist front kernel

// ---------------------------------------------------------------------------
// gemm device part: h = relu(x @ W1 + b1), inv = 1/max(||h||,eps), rows
// [rB, rE). TWO rows per wave iteration (W1 fragment reused 2x; fits the
// 85-VGPR budget of __launch_bounds__(256,6) needed for cooperative
// co-residency at 6 blocks/CU). Value-halving shuffle tree per row.
// ---------------------------------------------------------------------------
__device__ __forceinline__ void gemm_rows2(
    const float* __restrict__ x, const float* __restrict__ W1,
    const float* __restrict__ b1, float* __restrict__ h0,
    float* __restrict__ inv0, int rB, int rE, int wid, int totalWaves, int lane)
{
    float bias = b1[lane & 15];
    const bool s3 = (lane & 8) != 0;
    const bool s2 = (lane & 4) != 0;
    const bool s1 = (lane & 2) != 0;
    const bool s0 = (lane & 1) != 0;

    for (int g = rB + wid * 2; g < rE; g += totalWaves * 2) {
        int r0 = g;
        int r1 = (g + 1 < rE) ? g + 1 : rE - 1;

        float xv[2][8];
        {
            const float4* xp0 = (const float4*)(x + (size_t)r0 * F_IN + 8 * lane);
            const float4* xp1 = (const float4*)(x + (size_t)r1 * F_IN + 8 * lane);
            float4 a, b;
            a = xp0[0]; b = xp0[1];
            xv[0][0]=a.x; xv[0][1]=a.y; xv[0][2]=a.z; xv[0][3]=a.w;
            xv[0][4]=b.x; xv[0][5]=b.y; xv[0][6]=b.z; xv[0][7]=b.w;
            a = xp1[0]; b = xp1[1];
            xv[1][0]=a.x; xv[1][1]=a.y; xv[1][2]=a.z; xv[1][3]=a.w;
            xv[1][4]=b.x; xv[1][5]=b.y; xv[1][6]=b.z; xv[1][7]=b.w;
        }

        float acc[2][16];
#pragma unroll
        for (int i = 0; i < 2; ++i)
#pragma unroll
            for (int j = 0; j < 16; ++j) acc[i][j] = 0.f;

#pragma unroll
        for (int kk = 0; kk < 8; ++kk) {
            const float4* wp = (const float4*)(W1 + (size_t)(8 * lane + kk) * HID);
#pragma unroll
            for (int jj = 0; jj < 4; ++jj) {
                float4 t = wp[jj];
#pragma unroll
                for (int i = 0; i < 2; ++i) {
                    float xs = xv[i][kk];
                    acc[i][jj * 4 + 0] += xs * t.x;
                    acc[i][jj * 4 + 1] += xs * t.y;
                    acc[i][jj * 4 + 2] += xs * t.z;
                    acc[i][jj * 4 + 3] += xs * t.w;
                }
            }
        }

        int rr[2] = {r0, r1};
#pragma unroll
        for (int i = 0; i < 2; ++i) {
            float* a = acc[i];
#pragma unroll
            for (int u = 0; u < 8; ++u) {
                float k = s3 ? a[u + 8] : a[u];
                float s = s3 ? a[u] : a[u + 8];
                a[u] = k + __shfl_xor(s, 8);
            }
#pragma unroll
            for (int u = 0; u < 4; ++u) {
                float k = s2 ? a[u + 4] : a[u];
                float s = s2 ? a[u] : a[u + 4];
                a[u] = k + __shfl_xor(s, 4);
            }
#pragma unroll
            for (int u = 0; u < 2; ++u) {
                float k = s1 ? a[u + 2] : a[u];
                float s = s1 ? a[u] : a[u + 2];
                a[u] = k + __shfl_xor(s, 2);
            }
            {
                float k = s0 ? a[1] : a[0];
                float s = s0 ? a[0] : a[1];
                a[0] = k + __shfl_xor(s, 1);
            }
            a[0] += __shfl_xor(a[0], 16);
            a[0] += __shfl_xor(a[0], 32);

            float val = fmaxf(a[0] + bias, 0.f);
            bool live = (g + i < rE);
            if (live && lane < 16) h0[(size_t)rr[i] * HID + lane] = val;

            float qq = val * val;
            qq += __shfl_xor(qq, 1);
            qq += __shfl_xor(qq, 2);
            qq += __shfl_xor(qq, 4);
            qq += __shfl_xor(qq, 8);
            if (live && lane == 0) inv0[rr[i]] = 1.f / fmaxf(sqrtf(qq), 1e-12f);
        }
    }
}

// ---------------------------------------------------------------------------
// Attention phase (device fn): one wave per node, grid-stride over nodes.
// 4 lanes/edge, 16 edge slots, 4 unrolled slot groups (covers cnt<=64 with
// all esrc loads then all gathers in flight). Residual loop for cnt>64.
// Softmax shift-invariance: constant shift |beta| since cos in [-1,1].
// ---------------------------------------------------------------------------
__device__ __forceinline__ void agg_phase(
    const float* __restrict__ h, const float* __restrict__ inv,
    const int* __restrict__ esrc, const int* __restrict__ rowstart,
    const int* __restrict__ counts, const float* __restrict__ beta_p,
    float* __restrict__ hout, float* __restrict__ invout, int N, int G)
{
    int w = blockIdx.x * 4 + (threadIdx.x >> 6);
    int W = G * 4;
    int lane = threadIdx.x & 63;
    int q = lane & 3;        // feature quad
    int e = lane >> 2;       // edge slot 0..15

    float beta  = *beta_p;
    float shift = fabsf(beta);
    const float4* hp = (const float4*)h;

    for (int node = w; node < N; node += W) {
        float4 hd4  = hp[(size_t)node * 4 + q];
        float  invd = inv[node];
        int start = rowstart[node];
        int cnt   = counts[node];

        int t0 = e, t1 = e + 16, t2 = e + 32, t3 = e + 48;
        int s0 = esrc[start + (t0 < cnt ? t0 : 0)];
        int s1 = esrc[start + (t1 < cnt ? t1 : 0)];
        int s2 = esrc[start + (t2 < cnt ? t2 : 0)];
        int s3 = esrc[start + (t3 < cnt ? t3 : 0)];
        float4 a0 = hp[(size_t)s0 * 4 + q];
        float4 a1 = hp[(size_t)s1 * 4 + q];
        float4 a2 = hp[(size_t)s2 * 4 + q];
        float4 a3 = hp[(size_t)s3 * 4 + q];
        float i0 = inv[s0], i1 = inv[s1], i2 = inv[s2], i3 = inv[s3];

        float denom = 0.f;
        float4 acc = make_float4(0.f, 0.f, 0.f, 0.f);

#define AGG_SLOT(aa, ii, tt)                                                  \
        {                                                                     \
            float p = aa.x*hd4.x + aa.y*hd4.y + aa.z*hd4.z + aa.w*hd4.w;      \
            p += __shfl_xor(p, 1);                                            \
            p += __shfl_xor(p, 2);                                            \
            float wgt = __expf(beta * (p * invd * ii) - shift);               \
            wgt = (tt < cnt) ? wgt : 0.f;                                     \
            denom += wgt;                                                     \
            acc.x += wgt * aa.x; acc.y += wgt * aa.y;                         \
            acc.z += wgt * aa.z; acc.w += wgt * aa.w;                         \
        }
        AGG_SLOT(a0, i0, t0)
        AGG_SLOT(a1, i1, t1)
        AGG_SLOT(a2, i2, t2)
        AGG_SLOT(a3, i3, t3)
#undef AGG_SLOT

        for (int t = e + 64; t < cnt; t += 16) {
            int sr = esrc[start + t];
            float4 hs4 = hp[(size_t)sr * 4 + q];
            float invs = inv[sr];
            float p = hs4.x*hd4.x + hs4.y*hd4.y + hs4.z*hd4.z + hs4.w*hd4.w;
            p += __shfl_xor(p, 1);
            p += __shfl_xor(p, 2);
            float wgt = __expf(beta * (p * invd * invs) - shift);
            denom += wgt;
            acc.x += wgt * hs4.x;
            acc.y += wgt * hs4.y;
            acc.z += wgt * hs4.z;
            acc.w += wgt * hs4.w;
        }

#pragma unroll
        for (int off = 4; off <= 32; off <<= 1) {
            denom += __shfl_xor(denom, off);
            acc.x += __shfl_xor(acc.x, off);
            acc.y += __shfl_xor(acc.y, off);
            acc.z += __shfl_xor(acc.z, off);
            acc.w += __shfl_xor(acc.w, off);
        }
        float rd = 1.f / denom;        // denom>0 guaranteed by self-loop
        float4 o = make_float4(acc.x * rd, acc.y * rd, acc.z * rd, acc.w * rd);
        if (lane < 4) ((float4*)(hout + (size_t)node * HID))[q] = o;

        float ss = o.x*o.x + o.y*o.y + o.z*o.z + o.w*o.w;
        ss += __shfl_xor(ss, 1);
        ss += __shfl_xor(ss, 2);
        if (lane == 0) invout[node] = 1.f / fmaxf(sqrtf(ss), 1e-12f);
    }
}

// ---------------------------------------------------------------------------
// out phase (device fn): out = log_softmax(h2 @ W2 + b2), one wave per row,
// lane = class, grid-stride.
// ---------------------------------------------------------------------------
__device__ __forceinline__ void out_phase(
    const float* __restrict__ h2, const float* __restrict__ W2,
    const float* __restrict__ b2, float* __restrict__ out, int N, int G)
{
    int w = blockIdx.x * 4 + (threadIdx.x >> 6);
    int W = G * 4;
    int lane = threadIdx.x & 63;

    for (int row = w; row < N; row += W) {
        float hv = (lane < HID) ? h2[(size_t)row * HID + lane] : 0.f;
        float acc = b2[lane];
#pragma unroll
        for (int k = 0; k < HID; ++k) {
            float hk = __shfl(hv, k);
            acc += hk * W2[k * NCLS + lane];
        }
        float m = acc;
        for (int off = 32; off > 0; off >>= 1) m = fmaxf(m, __shfl_xor(m, off));
        float e = __expf(acc - m);
        float ssum = e;
        for (int off = 32; off > 0; off >>= 1) ssum += __shfl_xor(ssum, off);
        out[(size_t)row * NCLS + lane] = (acc - m) - __logf(ssum);
    }
}

// ---------------------------------------------------------------------------
// Front kernels (tiny): histogram of buckets + exclusive scan.
// ---------------------------------------------------------------------------
__global__ __launch_bounds__(256) void hist1_kernel(
    const int* __restrict__ dst, int E, int EV, int nbuck,
    int* __restrict__ bucketCount)
{
    __shared__ int h[NBUCK_MAX];
    int tid = threadIdx.x;
    for (int j = tid; j < nbuck; j += 256) h[j] = 0;
    __syncthreads();
    int base = blockIdx.x * EPB;
    for (int k = 0; k < EPB / 256; ++k) {
        int i = base + k * 256 + tid;
        if (i < EV) {
            int d = (i < E) ? dst[i] : (i - E);
            atomicAdd(&h[d >> 8], 1);
        }
    }
    __syncthreads();
    for (int j = tid; j < nbuck; j += 256)
        if (h[j]) atomicAdd(&bucketCount[j], h[j]);
}

__global__ __launch_bounds__(512) void bucket_scan_kernel(
    const int* __restrict__ bucketCount, int nbuck,
    int* __restrict__ bucketStart, int* __restrict__ gCursor)
{
    __shared__ int s[512];
    int t = threadIdx.x;
    int v = (t < nbuck) ? bucketCount[t] : 0;
    s[t] = v;
    __syncthreads();
    for (int off = 1; off < 512; off <<= 1) {
        int add = (t >= off) ? s[t - off] : 0;
        __syncthreads();
        s[t] += add;
        __syncthreads();
    }
    int incl = s[t];
    if (t < nbuck) {
        bucketStart[t] = incl - v;
        gCursor[t]     = incl - v;
        if (t == nbuck - 1) bucketStart[nbuck] = incl;
    }
}

// ---------------------------------------------------------------------------
// MEGA cooperative kernel:
//   phase A: blocks [0,C): partition edges -> staged  | blocks [C,G): gemm A
//   grid.sync
//   phase B: blocks [0,C): build CSR (grid-stride buckets) | gemm B
//   grid.sync
//   phase C: agg layer 1 (all blocks)
//   grid.sync
//   phase D: agg layer 2 (all blocks)
//   grid.sync
//   phase E: out (all blocks)
// Replaces 5 serialized launches (drain barriers) with 4 grid syncs and
// keeps the CSR||gemm overlap. One big dispatch => visible in rocprof.
// ---------------------------------------------------------------------------
struct MegaArgs {
    const int* src; const int* dst; int E; int EV; int nbuck;
    int* gCursor; unsigned* staged;
    const int* bucketStart; int* counts; int* rowstart; int* esrc; int N;
    const float* x; const float* W1; const float* b1;
    float* h0; float* inv0; float* h1; float* inv1; float* h2; float* inv2;
    const float* beta1; const float* beta2;
    const float* W2; const float* b2; float* out;
    int C; int G; int splitA;
};

__global__ __launch_bounds__(256, 6) void mega_kernel(MegaArgs a)
{
    cg::grid_group grid = cg::this_grid();
    __shared__ int lh[NBUCK_MAX];   // partition hist | build: hist(0:256)+scan(256:512)
    __shared__ int lg[NBUCK_MAX];   // partition gb   | build: cur(0:256)
    int bid = blockIdx.x;
    int tid = threadIdx.x;
    int lane = tid & 63;

    // ---------------- phase A: partition | gemm A ----------------
    if (bid < a.C) {
        int chunk = (a.EV + a.C - 1) / a.C;
        int base = bid * chunk;
        int lim  = base + chunk; if (lim > a.EV) lim = a.EV;

        for (int j = tid; j < a.nbuck; j += 256) lh[j] = 0;
        __syncthreads();
        for (int i = base + tid; i < lim; i += 256) {
            int d = (i < a.E) ? a.dst[i] : (i - a.E);
            atomicAdd(&lh[d >> 8], 1);
        }
        __syncthreads();
        for (int j = tid; j < a.nbuck; j += 256) {
            int c = lh[j];
            if (c) lg[j] = atomicAdd(&a.gCursor[j], c);
            lh[j] = 0;  // reuse as local cursor
        }
        __syncthreads();
        for (int i = base + tid; i < lim; i += 256) {
            int s, d;
            if (i < a.E) { s = a.src[i]; d = a.dst[i]; }
            else         { s = i - a.E;  d = s; }
            int bkt = d >> 8;
            int ofs = atomicAdd(&lh[bkt], 1);
            a.staged[lg[bkt] + ofs] = (unsigned)s | ((unsigned)(d & 255) << 17);
        }
    } else {
        int wid = (bid - a.C) * 4 + (tid >> 6);
        gemm_rows2(a.x, a.W1, a.b1, a.h0, a.inv0, 0, a.splitA,
                   wid, (a.G - a.C) * 4, lane);
    }
    grid.sync();

    // ---------------- phase B: build CSR | gemm B ----------------
    if (bid < a.C) {
        int* hist = lh;
        int* sArr = lh + 256;
        int* cur  = lg;
        for (int b = bid; b < a.nbuck; b += a.C) {
            int start = a.bucketStart[b];
            int end   = a.bucketStart[b + 1];

            hist[tid] = 0;
            __syncthreads();
            for (int i = start + tid; i < end; i += 256)
                atomicAdd(&hist[(a.staged[i] >> 17) & 255], 1);
            __syncthreads();

            int v = hist[tid];
            sArr[tid] = v;
            __syncthreads();
            for (int off = 1; off < 256; off <<= 1) {
                int add = (tid >= off) ? sArr[tid - off] : 0;
                __syncthreads();
                sArr[tid] += add;
                __syncthreads();
            }
            int excl = sArr[tid] - v;
            int dstg = b * 256 + tid;
            if (dstg < a.N) {
                a.counts[dstg]   = v;
                a.rowstart[dstg] = start + excl;
            }
            cur[tid] = start + excl;
            __syncthreads();

            for (int i = start + tid; i < end; i += 256) {
                unsigned pk = a.staged[i];
                int dl  = (pk >> 17) & 255;
                int pos = atomicAdd(&cur[dl], 1);
                a.esrc[pos] = (int)(pk & 0x1FFFFu);
            }
            __syncthreads();   // protect lh/lg before next bucket
        }
    } else {
        int wid = (bid - a.C) * 4 + (tid >> 6);
        gemm_rows2(a.x, a.W1, a.b1, a.h0, a.inv0, a.splitA, a.N,
                   wid, (a.G - a.C) * 4, lane);
    }
    grid.sync();

    // ---------------- phase C/D: attention layers ----------------
    agg_phase(a.h0, a.inv0, a.esrc, a.rowstart, a.counts, a.beta1,
              a.h1, a.inv1, a.N, a.G);
    grid.sync();
    agg_phase(a.h1, a.inv1, a.esrc, a.rowstart, a.counts, a.beta2,
              a.h2, a.inv2, a.N, a.G);
    grid.sync();

    // ---------------- phase E: classifier + log_softmax ----------------
    out_phase(a.h2, a.W2, a.b2, a.out, a.N, a.G);
}

// ---------------------------------------------------------------------------
extern "C" void kernel_launch(void* const* d_in, const int* in_sizes, int n_in,
                              void* d_out, int out_size, void* d_ws, size_t ws_size,
                              hipStream_t stream)
{
    const float* x     = (const float*)d_in[0];
    const int*   eidx  = (const int*)d_in[1];
    const float* W1    = (const float*)d_in[2];
    const float* b1    = (const float*)d_in[3];
    const float* W2    = (const float*)d_in[4];
    const float* b2    = (const float*)d_in[5];
    const float* beta1 = (const float*)d_in[6];
    const float* beta2 = (const float*)d_in[7];

    int N = in_sizes[0] / F_IN;       // 100000
    int E = in_sizes[1] / 2;          // 3200000
    const int* src = eidx;
    const int* dst = eidx + E;
    float* out = (float*)d_out;

    int EV    = E + N;                // virtual edges (incl. self-loops)
    int nbuck = (N + 255) / 256;      // 391

    char* wptr = (char*)d_ws;
    auto alloc = [&](size_t bytes) -> char* {
        char* p = wptr;
        wptr += (bytes + 255) / 256 * 256;
        return p;
    };
    float*    h0       = (float*)alloc((size_t)N * HID * 4);
    float*    inv0     = (float*)alloc((size_t)N * 4);
    float*    h1       = (float*)alloc((size_t)N * HID * 4);
    float*    inv1     = (float*)alloc((size_t)N * 4);
    float*    h2       = (float*)alloc((size_t)N * HID * 4);
    float*    inv2     = (float*)alloc((size_t)N * 4);
    int*      counts   = (int*)alloc((size_t)N * 4);
    int*      rowstart = (int*)alloc((size_t)(N + 1) * 4);
    int*      esrc     = (int*)alloc((size_t)EV * 4);
    unsigned* staged   = (unsigned*)alloc((size_t)EV * 4);
    int*      bucketCount = (int*)alloc((size_t)(nbuck + 1) * 4);
    int*      bucketStart = (int*)alloc((size_t)(nbuck + 1) * 4);
    int*      gCursor     = (int*)alloc((size_t)nbuck * 4);

    int ebBlocks = (EV + EPB - 1) / EPB;  // 403

    // cooperative grid size: query once (host-only, capture-safe)
    static int gBlocks = 0;
    if (gBlocks == 0) {
        hipDeviceProp_t prop;
        hipGetDeviceProperties(&prop, 0);
        int perCU = 0;
        hipOccupancyMaxActiveBlocksPerMultiprocessor(&perCU, mega_kernel, 256, 0);
        if (perCU < 1) perCU = 1;
        long long g = (long long)perCU * prop.multiProcessorCount;
        gBlocks = (g > 1536) ? 1536 : (int)g;
    }
    int G = gBlocks;
    int C = G / 4;                     // CSR-role blocks (384 when G=1536)
    if (C < 1) C = 1;
    int splitA = (int)((long long)N * 55 / 100);  // gemm rows in phase A

    // front: bucket histogram + scan (tiny)
    hipMemsetAsync(bucketCount, 0, (size_t)nbuck * 4, stream);
    hist1_kernel<<<ebBlocks, 256, 0, stream>>>(dst, E, EV, nbuck, bucketCount);
    bucket_scan_kernel<<<1, 512, 0, stream>>>(bucketCount, nbuck, bucketStart, gCursor);

    // mega cooperative kernel: partition||gemmA, build||gemmB, agg1, agg2, out
    MegaArgs ma;
    ma.src = src; ma.dst = dst; ma.E = E; ma.EV = EV; ma.nbuck = nbuck;
    ma.gCursor = gCursor; ma.staged = staged;
    ma.bucketStart = bucketStart; ma.counts = counts; ma.rowstart = rowstart;
    ma.esrc = esrc; ma.N = N;
    ma.x = x; ma.W1 = W1; ma.b1 = b1;
    ma.h0 = h0; ma.inv0 = inv0; ma.h1 = h1; ma.inv1 = inv1;
    ma.h2 = h2; ma.inv2 = inv2;
    ma.beta1 = beta1; ma.beta2 = beta2;
    ma.W2 = W2; ma.b2 = b2; ma.out = out;
    ma.C = C; ma.G = G; ma.splitA = splitA;

    void* kargs[] = { (void*)&ma };
    hipLaunchCooperativeKernel(reinterpret_cast<void*>(mega_kernel),
                               dim3(G), dim3(256), kargs, 0, stream);
}

// Round 4
// 564.453 us; speedup vs baseline: 2.4158x; 2.4158x over previous
//
#include <hip/hip_runtime.h>
#include <hip/hip_bf16.h>

#define F_IN 512
#define HID 16
#define NCLS 64
#define NBUCK_MAX 512     // LDS sizing; actual nbuck = ceil(N/256) = 391
#define EPB 8192          // edges per block in hist/partition

// ---------------- bf16 helpers (round-to-nearest-even, exact unpack) -------
__device__ __forceinline__ unsigned short rne_bf16(float f)
{
    unsigned u = __float_as_uint(f);
    unsigned r = u + 0x7FFFu + ((u >> 16) & 1u);
    return (unsigned short)(r >> 16);
}
__device__ __forceinline__ float bf16_to_f32(unsigned short b)
{
    return __uint_as_float(((unsigned)b) << 16);
}
__device__ __forceinline__ void unpack8(uint4 r, float* f)
{
    f[0] = __uint_as_float(r.x << 16); f[1] = __uint_as_float(r.x & 0xFFFF0000u);
    f[2] = __uint_as_float(r.y << 16); f[3] = __uint_as_float(r.y & 0xFFFF0000u);
    f[4] = __uint_as_float(r.z << 16); f[5] = __uint_as_float(r.z & 0xFFFF0000u);
    f[6] = __uint_as_float(r.w << 16); f[7] = __uint_as_float(r.w & 0xFFFF0000u);
}

// ---------------------------------------------------------------------------
// gemm device part: h0 = relu(x @ W1 + b1) stored as BF16 rows (32 B/node so
// the layer-1 gather set (3.2 MB + 0.4 MB inv) fits a 4 MB per-XCD L2);
// inv0 = 1/max(||h0_rounded||,eps) computed from the ROUNDED values so the
// stored features are exactly unit-norm under inv0 (cos self-consistency).
// FOUR rows per wave iteration (W1 fragment reused 4x). Value-halving
// shuffle tree: output j lands on lane&15==j.
// ---------------------------------------------------------------------------
__device__ __forceinline__ void gemm_rows(
    const float* __restrict__ x, const float* __restrict__ W1,
    const float* __restrict__ b1, unsigned short* __restrict__ hb0,
    float* __restrict__ inv0, int rB, int rE, int wid, int totalWaves, int lane)
{
    float bias = b1[lane & 15];
    const bool s3 = (lane & 8) != 0;
    const bool s2 = (lane & 4) != 0;
    const bool s1 = (lane & 2) != 0;
    const bool s0 = (lane & 1) != 0;

    for (int g = rB + wid * 4; g < rE; g += totalWaves * 4) {
        int r0 = g;
        int r1 = (g + 1 < rE) ? g + 1 : rE - 1;
        int r2 = (g + 2 < rE) ? g + 2 : rE - 1;
        int r3 = (g + 3 < rE) ? g + 3 : rE - 1;

        float xv[4][8];
        {
            const float4* xp0 = (const float4*)(x + (size_t)r0 * F_IN + 8 * lane);
            const float4* xp1 = (const float4*)(x + (size_t)r1 * F_IN + 8 * lane);
            const float4* xp2 = (const float4*)(x + (size_t)r2 * F_IN + 8 * lane);
            const float4* xp3 = (const float4*)(x + (size_t)r3 * F_IN + 8 * lane);
            float4 a, b;
            a = xp0[0]; b = xp0[1];
            xv[0][0]=a.x; xv[0][1]=a.y; xv[0][2]=a.z; xv[0][3]=a.w;
            xv[0][4]=b.x; xv[0][5]=b.y; xv[0][6]=b.z; xv[0][7]=b.w;
            a = xp1[0]; b = xp1[1];
            xv[1][0]=a.x; xv[1][1]=a.y; xv[1][2]=a.z; xv[1][3]=a.w;
            xv[1][4]=b.x; xv[1][5]=b.y; xv[1][6]=b.z; xv[1][7]=b.w;
            a = xp2[0]; b = xp2[1];
            xv[2][0]=a.x; xv[2][1]=a.y; xv[2][2]=a.z; xv[2][3]=a.w;
            xv[2][4]=b.x; xv[2][5]=b.y; xv[2][6]=b.z; xv[2][7]=b.w;
            a = xp3[0]; b = xp3[1];
            xv[3][0]=a.x; xv[3][1]=a.y; xv[3][2]=a.z; xv[3][3]=a.w;
            xv[3][4]=b.x; xv[3][5]=b.y; xv[3][6]=b.z; xv[3][7]=b.w;
        }

        float acc[4][16];
#pragma unroll
        for (int i = 0; i < 4; ++i)
#pragma unroll
            for (int j = 0; j < 16; ++j) acc[i][j] = 0.f;

#pragma unroll
        for (int kk = 0; kk < 8; ++kk) {
            const float4* wp = (const float4*)(W1 + (size_t)(8 * lane + kk) * HID);
#pragma unroll
            for (int jj = 0; jj < 4; ++jj) {
                float4 t = wp[jj];
#pragma unroll
                for (int i = 0; i < 4; ++i) {
                    float xs = xv[i][kk];
                    acc[i][jj * 4 + 0] += xs * t.x;
                    acc[i][jj * 4 + 1] += xs * t.y;
                    acc[i][jj * 4 + 2] += xs * t.z;
                    acc[i][jj * 4 + 3] += xs * t.w;
                }
            }
        }

        int rr[4] = {r0, r1, r2, r3};
#pragma unroll
        for (int i = 0; i < 4; ++i) {
            float* a = acc[i];
#pragma unroll
            for (int u = 0; u < 8; ++u) {
                float k = s3 ? a[u + 8] : a[u];
                float s = s3 ? a[u] : a[u + 8];
                a[u] = k + __shfl_xor(s, 8);
            }
#pragma unroll
            for (int u = 0; u < 4; ++u) {
                float k = s2 ? a[u + 4] : a[u];
                float s = s2 ? a[u] : a[u + 4];
                a[u] = k + __shfl_xor(s, 4);
            }
#pragma unroll
            for (int u = 0; u < 2; ++u) {
                float k = s1 ? a[u + 2] : a[u];
                float s = s1 ? a[u] : a[u + 2];
                a[u] = k + __shfl_xor(s, 2);
            }
            {
                float k = s0 ? a[1] : a[0];
                float s = s0 ? a[0] : a[1];
                a[0] = k + __shfl_xor(s, 1);
            }
            a[0] += __shfl_xor(a[0], 16);
            a[0] += __shfl_xor(a[0], 32);

            float val = fmaxf(a[0] + bias, 0.f);
            unsigned short vb = rne_bf16(val);
            float vr = bf16_to_f32(vb);

            bool live = (g + i < rE);
            if (live && lane < 16) hb0[(size_t)rr[i] * HID + lane] = vb;

            float qq = vr * vr;
            qq += __shfl_xor(qq, 1);
            qq += __shfl_xor(qq, 2);
            qq += __shfl_xor(qq, 4);
            qq += __shfl_xor(qq, 8);
            if (live && lane == 0) inv0[rr[i]] = 1.f / fmaxf(sqrtf(qq), 1e-12f);
        }
    }
}

// ---------------------------------------------------------------------------
// CSR build, pass 1: per-block LDS histogram of buckets (bucket = dst>>8).
// ---------------------------------------------------------------------------
__global__ __launch_bounds__(256) void hist1_kernel(
    const int* __restrict__ dst, int E, int EV, int nbuck,
    int* __restrict__ bucketCount)
{
    __shared__ int h[NBUCK_MAX];
    int tid = threadIdx.x;
    for (int j = tid; j < nbuck; j += 256) h[j] = 0;
    __syncthreads();
    int base = blockIdx.x * EPB;
    for (int k = 0; k < EPB / 256; ++k) {
        int i = base + k * 256 + tid;
        if (i < EV) {
            int d = (i < E) ? dst[i] : (i - E);
            atomicAdd(&h[d >> 8], 1);
        }
    }
    __syncthreads();
    for (int j = tid; j < nbuck; j += 256)
        if (h[j]) atomicAdd(&bucketCount[j], h[j]);
}

// ---------------------------------------------------------------------------
// CSR build, pass 2: single-WG exclusive scan of bucket counts.
// ---------------------------------------------------------------------------
__global__ __launch_bounds__(512) void bucket_scan_kernel(
    const int* __restrict__ bucketCount, int nbuck,
    int* __restrict__ bucketStart, int* __restrict__ gCursor)
{
    __shared__ int s[512];
    int t = threadIdx.x;
    int v = (t < nbuck) ? bucketCount[t] : 0;
    s[t] = v;
    __syncthreads();
    for (int off = 1; off < 512; off <<= 1) {
        int add = (t >= off) ? s[t - off] : 0;
        __syncthreads();
        s[t] += add;
        __syncthreads();
    }
    int incl = s[t];
    if (t < nbuck) {
        bucketStart[t] = incl - v;
        gCursor[t]     = incl - v;
        if (t == nbuck - 1) bucketStart[nbuck] = incl;
    }
}

// ---------------------------------------------------------------------------
// CSR pass 3 FUSED with gemm rows [rB,rE): blocks [0,csrBlocks) partition
// edges into bucket regions of `staged`; remaining blocks run gemm.
// staged entry packs src (17b) | dstLocal (8b) << 17.
// ---------------------------------------------------------------------------
__global__ __launch_bounds__(256) void part_gemm_kernel(
    const int* __restrict__ src, const int* __restrict__ dst,
    int E, int EV, int nbuck, int* __restrict__ gCursor,
    unsigned* __restrict__ staged,
    const float* __restrict__ x, const float* __restrict__ W1,
    const float* __restrict__ b1, unsigned short* __restrict__ hb0,
    float* __restrict__ inv0, int rB, int rE, int csrBlocks, int gemmWaves)
{
    __shared__ int h[NBUCK_MAX];
    __shared__ int gb[NBUCK_MAX];
    int tid = threadIdx.x;

    if ((int)blockIdx.x >= csrBlocks) {
        int wid = (((int)blockIdx.x - csrBlocks) * 256 + tid) >> 6;
        gemm_rows(x, W1, b1, hb0, inv0, rB, rE, wid, gemmWaves, tid & 63);
        return;
    }

    for (int j = tid; j < nbuck; j += 256) h[j] = 0;
    __syncthreads();

    int base = blockIdx.x * EPB;
    // pass A: local histogram
    for (int k = 0; k < EPB / 256; ++k) {
        int i = base + k * 256 + tid;
        if (i < EV) {
            int d = (i < E) ? dst[i] : (i - E);
            atomicAdd(&h[d >> 8], 1);
        }
    }
    __syncthreads();
    // reserve contiguous chunks
    for (int j = tid; j < nbuck; j += 256) {
        int c = h[j];
        if (c) gb[j] = atomicAdd(&gCursor[j], c);
        h[j] = 0;  // reuse as local cursor
    }
    __syncthreads();
    // pass B: re-read edges, write packed entries into reserved chunks
    for (int k = 0; k < EPB / 256; ++k) {
        int i = base + k * 256 + tid;
        if (i < EV) {
            int s, d;
            if (i < E) { s = src[i]; d = dst[i]; }
            else       { s = i - E;  d = s; }
            int bkt = d >> 8;
            int ofs = atomicAdd(&h[bkt], 1);
            staged[gb[bkt] + ofs] = (unsigned)s | ((unsigned)(d & 255) << 17);
        }
    }
}

// ---------------------------------------------------------------------------
// CSR pass 4 FUSED with gemm rows [rB,rE): blocks [0,csrBlocks) build
// counts/rowstart/esrc (one block per bucket); remaining blocks run gemm.
// ---------------------------------------------------------------------------
__global__ __launch_bounds__(256) void build_gemm_kernel(
    const unsigned* __restrict__ staged, const int* __restrict__ bucketStart,
    int* __restrict__ counts, int* __restrict__ rowstart,
    int* __restrict__ esrc, int N,
    const float* __restrict__ x, const float* __restrict__ W1,
    const float* __restrict__ b1, unsigned short* __restrict__ hb0,
    float* __restrict__ inv0, int rB, int rE, int csrBlocks, int gemmWaves)
{
    __shared__ int hist[256];
    __shared__ int s[256];
    __shared__ int cur[256];
    int tid = threadIdx.x;

    if ((int)blockIdx.x >= csrBlocks) {
        int wid = (((int)blockIdx.x - csrBlocks) * 256 + tid) >> 6;
        gemm_rows(x, W1, b1, hb0, inv0, rB, rE, wid, gemmWaves, tid & 63);
        return;
    }

    int b   = blockIdx.x;
    int start = bucketStart[b];
    int end   = bucketStart[b + 1];

    hist[tid] = 0;
    __syncthreads();
    for (int i = start + tid; i < end; i += 256)
        atomicAdd(&hist[(staged[i] >> 17) & 255], 1);
    __syncthreads();

    int v = hist[tid];
    s[tid] = v;
    __syncthreads();
    for (int off = 1; off < 256; off <<= 1) {
        int add = (tid >= off) ? s[tid - off] : 0;
        __syncthreads();
        s[tid] += add;
        __syncthreads();
    }
    int excl = s[tid] - v;
    int dstg = b * 256 + tid;
    if (dstg < N) {
        counts[dstg]   = v;
        rowstart[dstg] = start + excl;
    }
    cur[tid] = start + excl;
    __syncthreads();

    for (int i = start + tid; i < end; i += 256) {
        unsigned pk = staged[i];
        int dl  = (pk >> 17) & 255;
        int pos = atomicAdd(&cur[dl], 1);
        esrc[pos] = (int)(pk & 0x1FFFFu);
    }
}

// ---------------------------------------------------------------------------
// Attention layer on BF16 features: ONE WAVE PER NODE, 2 lanes per edge
// (half = lane&1 owns features 8*half..8*half+7; e = lane>>1 = edge slot
// 0..31). 32 concurrent 16-B gathers per wave; 2 unrolled slot groups cover
// cnt <= 64 with all esrc loads then all gathers in flight. The bf16 rows
// (32 B/node, 3.2 MB total) + inv (0.4 MB) fit a 4 MB per-XCD L2 -> gathers
// become L2 hits (fp32 h was 6.8 MB and thrashed; mega-kernel rocprof
// showed 1.6 GB FETCH from exactly this).
// OUTF32=0: write bf16 row + inv (feeds next attention layer).
// OUTF32=1: write fp32 row, no inv (feeds classifier).
// Softmax shift-invariance: constant shift |beta| since cos in [-1,1].
// ---------------------------------------------------------------------------
template<int OUTF32>
__global__ __launch_bounds__(256) void agg_kernel(
    const unsigned short* __restrict__ hb, const float* __restrict__ inv,
    const int* __restrict__ esrc, const int* __restrict__ rowstart,
    const int* __restrict__ counts, const float* __restrict__ beta_p,
    unsigned short* __restrict__ houtb, float* __restrict__ houtf,
    float* __restrict__ invout, int N)
{
    int node = (blockIdx.x * blockDim.x + threadIdx.x) >> 6;
    if (node >= N) return;
    int lane = threadIdx.x & 63;
    int half = lane & 1;     // feature half: features 8*half..8*half+7
    int e    = lane >> 1;    // edge slot 0..31

    float beta  = *beta_p;
    float shift = fabsf(beta);
    const uint4* hbp = (const uint4*)hb;     // 2 uint4 per node row

    uint4 rawd = hbp[(size_t)node * 2 + half];
    float hd[8]; unpack8(rawd, hd);
    float invd = inv[node];
    int start = rowstart[node];
    int cnt   = counts[node];

    // ---- issue both slot-groups' esrc loads, then all gathers ----
    int t0 = e, t1 = e + 32;
    int s0 = esrc[start + (t0 < cnt ? t0 : 0)];
    int s1 = esrc[start + (t1 < cnt ? t1 : 0)];
    uint4 r0 = hbp[(size_t)s0 * 2 + half];
    uint4 r1 = hbp[(size_t)s1 * 2 + half];
    float i0 = inv[s0], i1 = inv[s1];

    float denom = 0.f;
    float acc[8];
#pragma unroll
    for (int j = 0; j < 8; ++j) acc[j] = 0.f;

#define AGG_SLOT(rr, ii, tt)                                                  \
    {                                                                         \
        float hs[8]; unpack8(rr, hs);                                         \
        float p = hs[0]*hd[0] + hs[1]*hd[1] + hs[2]*hd[2] + hs[3]*hd[3]       \
                + hs[4]*hd[4] + hs[5]*hd[5] + hs[6]*hd[6] + hs[7]*hd[7];      \
        p += __shfl_xor(p, 1);                                                \
        float w = __expf(beta * (p * invd * ii) - shift);                     \
        w = (tt < cnt) ? w : 0.f;                                             \
        denom += w;                                                           \
        _Pragma("unroll")                                                     \
        for (int j = 0; j < 8; ++j) acc[j] += w * hs[j];                      \
    }
    AGG_SLOT(r0, i0, t0)
    AGG_SLOT(r1, i1, t1)

    // residual edges (cnt > 64): essentially never taken, kept for correctness
    for (int t = e + 64; t < cnt; t += 32) {
        int sr = esrc[start + t];
        uint4 rr = hbp[(size_t)sr * 2 + half];
        float invs = inv[sr];
        float hs[8]; unpack8(rr, hs);
        float p = hs[0]*hd[0] + hs[1]*hd[1] + hs[2]*hd[2] + hs[3]*hd[3]
                + hs[4]*hd[4] + hs[5]*hd[5] + hs[6]*hd[6] + hs[7]*hd[7];
        p += __shfl_xor(p, 1);
        float w = __expf(beta * (p * invd * invs) - shift);
        denom += w;
#pragma unroll
        for (int j = 0; j < 8; ++j) acc[j] += w * hs[j];
    }
#undef AGG_SLOT

    // reduce across the 32 edge slots (lane bits 1..5); halves stay separate
#pragma unroll
    for (int off = 2; off <= 32; off <<= 1) {
        denom += __shfl_xor(denom, off);
#pragma unroll
        for (int j = 0; j < 8; ++j) acc[j] += __shfl_xor(acc[j], off);
    }
    float rdn = 1.f / denom;       // denom>0 guaranteed by self-loop
    float o[8];
#pragma unroll
    for (int j = 0; j < 8; ++j) o[j] = acc[j] * rdn;

    if (OUTF32) {
        if (lane < 2) {
            float4 oa = make_float4(o[0], o[1], o[2], o[3]);
            float4 ob = make_float4(o[4], o[5], o[6], o[7]);
            float4* op = (float4*)(houtf + (size_t)node * HID) + lane * 2;
            op[0] = oa;
            op[1] = ob;
        }
    } else {
        unsigned short pb[8];
        float orr[8];
#pragma unroll
        for (int j = 0; j < 8; ++j) {
            pb[j]  = rne_bf16(o[j]);
            orr[j] = bf16_to_f32(pb[j]);
        }
        if (lane < 2) {
            uint4 pk;
            pk.x = (unsigned)pb[0] | ((unsigned)pb[1] << 16);
            pk.y = (unsigned)pb[2] | ((unsigned)pb[3] << 16);
            pk.z = (unsigned)pb[4] | ((unsigned)pb[5] << 16);
            pk.w = (unsigned)pb[6] | ((unsigned)pb[7] << 16);
            ((uint4*)houtb)[(size_t)node * 2 + lane] = pk;
        }
        float ssl = orr[0]*orr[0] + orr[1]*orr[1] + orr[2]*orr[2] + orr[3]*orr[3]
                  + orr[4]*orr[4] + orr[5]*orr[5] + orr[6]*orr[6] + orr[7]*orr[7];
        ssl += __shfl_xor(ssl, 1);
        if (lane == 0) invout[node] = 1.f / fmaxf(sqrtf(ssl), 1e-12f);
    }
}

// ---------------------------------------------------------------------------
// K5: out = log_softmax(h2 @ W2 + b2). One wave per row, lane = class.
// ---------------------------------------------------------------------------
__global__ __launch_bounds__(256) void out_kernel(
    const float* __restrict__ h2, const float* __restrict__ W2,
    const float* __restrict__ b2, float* __restrict__ out, int N)
{
    int wave = (blockIdx.x * blockDim.x + threadIdx.x) >> 6;
    int lane = threadIdx.x & 63;
    if (wave >= N) return;

    float hv = (lane < HID) ? h2[(size_t)wave * HID + lane] : 0.f;
    float acc = b2[lane];
#pragma unroll
    for (int k = 0; k < HID; ++k) {
        float hk = __shfl(hv, k);
        acc += hk * W2[k * NCLS + lane];
    }
    float m = acc;
    for (int off = 32; off > 0; off >>= 1) m = fmaxf(m, __shfl_xor(m, off));
    float e = __expf(acc - m);
    float ssum = e;
    for (int off = 32; off > 0; off >>= 1) ssum += __shfl_xor(ssum, off);
    out[(size_t)wave * NCLS + lane] = (acc - m) - __logf(ssum);
}

// ---------------------------------------------------------------------------
extern "C" void kernel_launch(void* const* d_in, const int* in_sizes, int n_in,
                              void* d_out, int out_size, void* d_ws, size_t ws_size,
                              hipStream_t stream)
{
    const float* x     = (const float*)d_in[0];
    const int*   eidx  = (const int*)d_in[1];
    const float* W1    = (const float*)d_in[2];
    const float* b1    = (const float*)d_in[3];
    const float* W2    = (const float*)d_in[4];
    const float* b2    = (const float*)d_in[5];
    const float* beta1 = (const float*)d_in[6];
    const float* beta2 = (const float*)d_in[7];

    int N = in_sizes[0] / F_IN;       // 100000
    int E = in_sizes[1] / 2;          // 3200000
    const int* src = eidx;
    const int* dst = eidx + E;
    float* out = (float*)d_out;

    int EV    = E + N;                // virtual edges (incl. self-loops)
    int nbuck = (N + 255) / 256;      // 391

    char* wptr = (char*)d_ws;
    auto alloc = [&](size_t bytes) -> char* {
        char* p = wptr;
        wptr += (bytes + 255) / 256 * 256;
        return p;
    };
    unsigned short* hb0 = (unsigned short*)alloc((size_t)N * HID * 2);
    unsigned short* hb1 = (unsigned short*)alloc((size_t)N * HID * 2);
    float*    h2       = (float*)alloc((size_t)N * HID * 4);
    float*    inv0     = (float*)alloc((size_t)N * 4);
    float*    inv1     = (float*)alloc((size_t)N * 4);
    int*      counts   = (int*)alloc((size_t)N * 4);
    int*      rowstart = (int*)alloc((size_t)(N + 1) * 4);
    int*      esrc     = (int*)alloc((size_t)EV * 4);
    unsigned* staged   = (unsigned*)alloc((size_t)EV * 4);
    int*      bucketCount = (int*)alloc((size_t)(nbuck + 1) * 4);
    int*      bucketStart = (int*)alloc((size_t)(nbuck + 1) * 4);
    int*      gCursor     = (int*)alloc((size_t)nbuck * 4);

    int ebBlocks = (EV + EPB - 1) / EPB;  // 403

    // CSR build front (tiny): hist + scan
    hipMemsetAsync(bucketCount, 0, (size_t)nbuck * 4, stream);
    hist1_kernel<<<ebBlocks, 256, 0, stream>>>(dst, E, EV, nbuck, bucketCount);
    bucket_scan_kernel<<<1, 512, 0, stream>>>(bucketCount, nbuck, bucketStart, gCursor);

    // partition + gemm rows [0, rSplit) overlapped in one launch;
    // build_csr + gemm rows [rSplit, N) in the next. CSR blocks come first
    // in dispatch order so the CSR chain isn't delayed.
    int rSplit   = 60000;
    int gcBlocks = 1024;   // 4096 gemm waves alongside partition
    int gdBlocks = 768;    // 3072 gemm waves alongside build_csr
    part_gemm_kernel<<<ebBlocks + gcBlocks, 256, 0, stream>>>(
        src, dst, E, EV, nbuck, gCursor, staged,
        x, W1, b1, hb0, inv0, 0, rSplit, ebBlocks, gcBlocks * 4);
    build_gemm_kernel<<<nbuck + gdBlocks, 256, 0, stream>>>(
        staged, bucketStart, counts, rowstart, esrc, N,
        x, W1, b1, hb0, inv0, rSplit, N, nbuck, gdBlocks * 4);

    // two attention layers: one wave per node, bf16 feature gathers
    int aggBlocks = (N + 3) / 4;   // 4 waves (nodes) per 256-thread block
    agg_kernel<0><<<aggBlocks, 256, 0, stream>>>(hb0, inv0, esrc, rowstart, counts,
                                                 beta1, hb1, (float*)nullptr, inv1, N);
    agg_kernel<1><<<aggBlocks, 256, 0, stream>>>(hb1, inv1, esrc, rowstart, counts,
                                                 beta2, (unsigned short*)nullptr, h2,
                                                 (float*)nullptr, N);

    // out = log_softmax(h2@W2+b2)
    out_kernel<<<(N * 64 + 255) / 256, 256, 0, stream>>>(h2, W2, b2, out, N);
}

// Round 5
// 559.158 us; speedup vs baseline: 2.4386x; 1.0095x over previous
//
#include <hip/hip_runtime.h>
#include <hip/hip_bf16.h>

#define F_IN 512
#define HID 16
#define NCLS 64
#define NBUCK_MAX 512     // LDS sizing; actual nbuck = ceil(N/256) = 391
#define EPB 8192          // edges per block in hist/partition

// ---------------------------------------------------------------------------
// gemm device part: h0 = relu(x @ W1 + b1), inv0 = 1/max(||h0||,eps), rows
// [rB, rE). FOUR ROWS PER WAVE ITERATION (W1 fragment loaded once from L1,
// applied to 4 x-rows). Lane owns k in [8*lane, 8*lane+8). Value-halving
// shuffle tree: 17 shuffles/row, output j lands on lane&15==j.
// ---------------------------------------------------------------------------
__device__ __forceinline__ void gemm_rows(
    const float* __restrict__ x, const float* __restrict__ W1,
    const float* __restrict__ b1, float* __restrict__ h0,
    float* __restrict__ inv0, int rB, int rE, int wid, int totalWaves, int lane)
{
    float bias = b1[lane & 15];
    const bool s3 = (lane & 8) != 0;
    const bool s2 = (lane & 4) != 0;
    const bool s1 = (lane & 2) != 0;
    const bool s0 = (lane & 1) != 0;

    for (int g = rB + wid * 4; g < rE; g += totalWaves * 4) {
        int r0 = g;
        int r1 = (g + 1 < rE) ? g + 1 : rE - 1;
        int r2 = (g + 2 < rE) ? g + 2 : rE - 1;
        int r3 = (g + 3 < rE) ? g + 3 : rE - 1;

        float xv[4][8];
        {
            const float4* xp0 = (const float4*)(x + (size_t)r0 * F_IN + 8 * lane);
            const float4* xp1 = (const float4*)(x + (size_t)r1 * F_IN + 8 * lane);
            const float4* xp2 = (const float4*)(x + (size_t)r2 * F_IN + 8 * lane);
            const float4* xp3 = (const float4*)(x + (size_t)r3 * F_IN + 8 * lane);
            float4 a, b;
            a = xp0[0]; b = xp0[1];
            xv[0][0]=a.x; xv[0][1]=a.y; xv[0][2]=a.z; xv[0][3]=a.w;
            xv[0][4]=b.x; xv[0][5]=b.y; xv[0][6]=b.z; xv[0][7]=b.w;
            a = xp1[0]; b = xp1[1];
            xv[1][0]=a.x; xv[1][1]=a.y; xv[1][2]=a.z; xv[1][3]=a.w;
            xv[1][4]=b.x; xv[1][5]=b.y; xv[1][6]=b.z; xv[1][7]=b.w;
            a = xp2[0]; b = xp2[1];
            xv[2][0]=a.x; xv[2][1]=a.y; xv[2][2]=a.z; xv[2][3]=a.w;
            xv[2][4]=b.x; xv[2][5]=b.y; xv[2][6]=b.z; xv[2][7]=b.w;
            a = xp3[0]; b = xp3[1];
            xv[3][0]=a.x; xv[3][1]=a.y; xv[3][2]=a.z; xv[3][3]=a.w;
            xv[3][4]=b.x; xv[3][5]=b.y; xv[3][6]=b.z; xv[3][7]=b.w;
        }

        float acc[4][16];
#pragma unroll
        for (int i = 0; i < 4; ++i)
#pragma unroll
            for (int j = 0; j < 16; ++j) acc[i][j] = 0.f;

#pragma unroll
        for (int kk = 0; kk < 8; ++kk) {
            const float4* wp = (const float4*)(W1 + (size_t)(8 * lane + kk) * HID);
#pragma unroll
            for (int jj = 0; jj < 4; ++jj) {
                float4 t = wp[jj];
#pragma unroll
                for (int i = 0; i < 4; ++i) {
                    float xs = xv[i][kk];
                    acc[i][jj * 4 + 0] += xs * t.x;
                    acc[i][jj * 4 + 1] += xs * t.y;
                    acc[i][jj * 4 + 2] += xs * t.z;
                    acc[i][jj * 4 + 3] += xs * t.w;
                }
            }
        }

        int rr[4] = {r0, r1, r2, r3};
#pragma unroll
        for (int i = 0; i < 4; ++i) {
            float* a = acc[i];
#pragma unroll
            for (int u = 0; u < 8; ++u) {
                float k = s3 ? a[u + 8] : a[u];
                float s = s3 ? a[u] : a[u + 8];
                a[u] = k + __shfl_xor(s, 8);
            }
#pragma unroll
            for (int u = 0; u < 4; ++u) {
                float k = s2 ? a[u + 4] : a[u];
                float s = s2 ? a[u] : a[u + 4];
                a[u] = k + __shfl_xor(s, 4);
            }
#pragma unroll
            for (int u = 0; u < 2; ++u) {
                float k = s1 ? a[u + 2] : a[u];
                float s = s1 ? a[u] : a[u + 2];
                a[u] = k + __shfl_xor(s, 2);
            }
            {
                float k = s0 ? a[1] : a[0];
                float s = s0 ? a[0] : a[1];
                a[0] = k + __shfl_xor(s, 1);
            }
            a[0] += __shfl_xor(a[0], 16);
            a[0] += __shfl_xor(a[0], 32);

            float val = fmaxf(a[0] + bias, 0.f);
            bool live = (g + i < rE);
            if (live && lane < 16) h0[(size_t)rr[i] * HID + lane] = val;

            float qq = val * val;
            qq += __shfl_xor(qq, 1);
            qq += __shfl_xor(qq, 2);
            qq += __shfl_xor(qq, 4);
            qq += __shfl_xor(qq, 8);
            if (live && lane == 0) inv0[rr[i]] = 1.f / fmaxf(sqrtf(qq), 1e-12f);
        }
    }
}

// ---------------------------------------------------------------------------
// CSR passes 1+2 FUSED: per-block LDS histogram -> global atomicAdd; the
// LAST-arriving block (done-counter) performs the 512-slot exclusive scan.
// Reads of bucketCount in the scan use atomicAdd(p,0) (device-scope RMW) so
// they observe all other blocks' atomics regardless of XCD/L1 state.
// ---------------------------------------------------------------------------
__global__ __launch_bounds__(256) void histscan_kernel(
    const int* __restrict__ dst, int E, int EV, int nbuck, int nblocks,
    int* __restrict__ bucketCount, int* __restrict__ doneCnt,
    int* __restrict__ bucketStart, int* __restrict__ gCursor)
{
    __shared__ int h[NBUCK_MAX];
    __shared__ int s[NBUCK_MAX];
    __shared__ int lastFlag;
    int tid = threadIdx.x;
    for (int j = tid; j < nbuck; j += 256) h[j] = 0;
    __syncthreads();
    int base = blockIdx.x * EPB;
    for (int k = 0; k < EPB / 256; ++k) {
        int i = base + k * 256 + tid;
        if (i < EV) {
            int d = (i < E) ? dst[i] : (i - E);
            atomicAdd(&h[d >> 8], 1);
        }
    }
    __syncthreads();
    for (int j = tid; j < nbuck; j += 256)
        if (h[j]) atomicAdd(&bucketCount[j], h[j]);

    __threadfence();
    __syncthreads();
    if (tid == 0) {
        int prev = atomicAdd(doneCnt, 1);
        lastFlag = (prev == nblocks - 1) ? 1 : 0;
    }
    __syncthreads();
    if (!lastFlag) return;

    // ---- last block: exclusive scan of bucketCount[0..nbuck) ----
    int i1 = tid + 256;
    int v0 = (tid < nbuck) ? atomicAdd(&bucketCount[tid], 0) : 0;
    int v1 = (i1  < nbuck) ? atomicAdd(&bucketCount[i1],  0) : 0;
    s[tid] = v0;
    s[i1]  = v1;
    __syncthreads();
    for (int off = 1; off < 512; off <<= 1) {
        int a0 = (tid >= off) ? s[tid - off] : 0;
        int a1 = (i1  >= off) ? s[i1  - off] : 0;
        __syncthreads();
        s[tid] += a0;
        s[i1]  += a1;
        __syncthreads();
    }
    int incl0 = s[tid], incl1 = s[i1];
    if (tid < nbuck) { bucketStart[tid] = incl0 - v0; gCursor[tid] = incl0 - v0; }
    if (i1  < nbuck) { bucketStart[i1]  = incl1 - v1; gCursor[i1]  = incl1 - v1; }
    if (tid == nbuck - 1) bucketStart[nbuck] = incl0;
    if (i1  == nbuck - 1) bucketStart[nbuck] = incl1;
}

// ---------------------------------------------------------------------------
// CSR pass 3 FUSED with gemm rows [rB,rE): blocks [0,csrBlocks) partition
// edges into bucket regions of `staged`; remaining blocks run gemm. The two
// sides touch disjoint data so they overlap on the device.
// staged entry packs src (17b) | dstLocal (8b) << 17.
// ---------------------------------------------------------------------------
__global__ __launch_bounds__(256) void part_gemm_kernel(
    const int* __restrict__ src, const int* __restrict__ dst,
    int E, int EV, int nbuck, int* __restrict__ gCursor,
    unsigned* __restrict__ staged,
    const float* __restrict__ x, const float* __restrict__ W1,
    const float* __restrict__ b1, float* __restrict__ h0,
    float* __restrict__ inv0, int rB, int rE, int csrBlocks, int gemmWaves)
{
    __shared__ int h[NBUCK_MAX];
    __shared__ int gb[NBUCK_MAX];
    int tid = threadIdx.x;

    if ((int)blockIdx.x >= csrBlocks) {
        int wid = (((int)blockIdx.x - csrBlocks) * 256 + tid) >> 6;
        gemm_rows(x, W1, b1, h0, inv0, rB, rE, wid, gemmWaves, tid & 63);
        return;
    }

    for (int j = tid; j < nbuck; j += 256) h[j] = 0;
    __syncthreads();

    int base = blockIdx.x * EPB;
    // pass A: local histogram
    for (int k = 0; k < EPB / 256; ++k) {
        int i = base + k * 256 + tid;
        if (i < EV) {
            int d = (i < E) ? dst[i] : (i - E);
            atomicAdd(&h[d >> 8], 1);
        }
    }
    __syncthreads();
    // reserve contiguous chunks
    for (int j = tid; j < nbuck; j += 256) {
        int c = h[j];
        if (c) gb[j] = atomicAdd(&gCursor[j], c);
        h[j] = 0;  // reuse as local cursor
    }
    __syncthreads();
    // pass B: re-read edges, write packed entries into reserved chunks
    for (int k = 0; k < EPB / 256; ++k) {
        int i = base + k * 256 + tid;
        if (i < EV) {
            int s, d;
            if (i < E) { s = src[i]; d = dst[i]; }
            else       { s = i - E;  d = s; }
            int bkt = d >> 8;
            int ofs = atomicAdd(&h[bkt], 1);
            staged[gb[bkt] + ofs] = (unsigned)s | ((unsigned)(d & 255) << 17);
        }
    }
}

// ---------------------------------------------------------------------------
// CSR pass 4 FUSED with gemm rows [rB,rE): blocks [0,csrBlocks) build
// counts/rowstart/esrc (one block per bucket); remaining blocks run gemm.
// ---------------------------------------------------------------------------
__global__ __launch_bounds__(256) void build_gemm_kernel(
    const unsigned* __restrict__ staged, const int* __restrict__ bucketStart,
    int* __restrict__ counts, int* __restrict__ rowstart,
    int* __restrict__ esrc, int N,
    const float* __restrict__ x, const float* __restrict__ W1,
    const float* __restrict__ b1, float* __restrict__ h0,
    float* __restrict__ inv0, int rB, int rE, int csrBlocks, int gemmWaves)
{
    __shared__ int hist[256];
    __shared__ int s[256];
    __shared__ int cur[256];
    int tid = threadIdx.x;

    if ((int)blockIdx.x >= csrBlocks) {
        int wid = (((int)blockIdx.x - csrBlocks) * 256 + tid) >> 6;
        gemm_rows(x, W1, b1, h0, inv0, rB, rE, wid, gemmWaves, tid & 63);
        return;
    }

    int b   = blockIdx.x;
    int start = bucketStart[b];
    int end   = bucketStart[b + 1];

    hist[tid] = 0;
    __syncthreads();
    for (int i = start + tid; i < end; i += 256)
        atomicAdd(&hist[(staged[i] >> 17) & 255], 1);
    __syncthreads();

    int v = hist[tid];
    s[tid] = v;
    __syncthreads();
    for (int off = 1; off < 256; off <<= 1) {
        int add = (tid >= off) ? s[tid - off] : 0;
        __syncthreads();
        s[tid] += add;
        __syncthreads();
    }
    int excl = s[tid] - v;
    int dstg = b * 256 + tid;
    if (dstg < N) {
        counts[dstg]   = v;
        rowstart[dstg] = start + excl;
    }
    cur[tid] = start + excl;
    __syncthreads();

    for (int i = start + tid; i < end; i += 256) {
        unsigned pk = staged[i];
        int dl  = (pk >> 17) & 255;
        int pos = atomicAdd(&cur[dl], 1);
        esrc[pos] = (int)(pk & 0x1FFFFu);
    }
}

// ---------------------------------------------------------------------------
// Attention layer: ONE WAVE PER NODE, 4 lanes per edge (q = feature quad,
// e = edge slot 0..15). 4 unrolled slot groups (64 edges) with all esrc
// loads issued first, then all gathers. Residual loop for cnt>64.
// Softmax shift-invariance: constant shift |beta| since cos in [-1,1].
// LAST=0: write h1 row + inv1 (feeds layer 2).
// LAST=1: FUSED CLASSIFIER — broadcast the in-register h2 row to all 64
//   lanes (12 shuffles), lane=class computes the W2 logit + log_softmax and
//   writes `out` directly. h2 never touches memory; the separate out_kernel
//   launch, its drain, and 12.8 MB of h2 traffic are eliminated. Logits use
//   the identical fp32 h2 values in the identical summation order as the
//   split version, so absmax is unchanged.
// ---------------------------------------------------------------------------
template<int LAST>
__global__ __launch_bounds__(256) void agg_kernel(
    const float* __restrict__ h, const float* __restrict__ inv,
    const int* __restrict__ esrc, const int* __restrict__ rowstart,
    const int* __restrict__ counts, const float* __restrict__ beta_p,
    float* __restrict__ hout, float* __restrict__ invout,
    const float* __restrict__ W2, const float* __restrict__ b2,
    float* __restrict__ out, int N)
{
    int node = (blockIdx.x * blockDim.x + threadIdx.x) >> 6;
    if (node >= N) return;
    int lane = threadIdx.x & 63;
    int q = lane & 3;        // feature quad: features 4q..4q+3
    int e = lane >> 2;       // edge slot 0..15

    float beta  = *beta_p;
    float shift = fabsf(beta);
    float4 hd4  = ((const float4*)(h + (size_t)node * HID))[q];
    float  invd = inv[node];
    int start = rowstart[node];
    int cnt   = counts[node];

    // ---- issue all 4 slot-groups' esrc loads (independent addresses) ----
    int t0 = e, t1 = e + 16, t2 = e + 32, t3 = e + 48;
    int s0 = esrc[start + (t0 < cnt ? t0 : 0)];
    int s1 = esrc[start + (t1 < cnt ? t1 : 0)];
    int s2 = esrc[start + (t2 < cnt ? t2 : 0)];
    int s3 = esrc[start + (t3 < cnt ? t3 : 0)];
    // ---- issue all gathers ----
    const float4* hp = (const float4*)h;
    float4 a0 = hp[(size_t)s0 * 4 + q];
    float4 a1 = hp[(size_t)s1 * 4 + q];
    float4 a2 = hp[(size_t)s2 * 4 + q];
    float4 a3 = hp[(size_t)s3 * 4 + q];
    float i0 = inv[s0], i1 = inv[s1], i2 = inv[s2], i3 = inv[s3];

    float denom = 0.f;
    float4 acc = make_float4(0.f, 0.f, 0.f, 0.f);

#define AGG_SLOT(aa, ii, tt)                                                  \
    {                                                                         \
        float p = aa.x * hd4.x + aa.y * hd4.y + aa.z * hd4.z + aa.w * hd4.w;  \
        p += __shfl_xor(p, 1);                                                \
        p += __shfl_xor(p, 2);                                                \
        float w = __expf(beta * (p * invd * ii) - shift);                     \
        w = (tt < cnt) ? w : 0.f;                                             \
        denom += w;                                                           \
        acc.x += w * aa.x; acc.y += w * aa.y;                                 \
        acc.z += w * aa.z; acc.w += w * aa.w;                                 \
    }
    AGG_SLOT(a0, i0, t0)
    AGG_SLOT(a1, i1, t1)
    AGG_SLOT(a2, i2, t2)
    AGG_SLOT(a3, i3, t3)
#undef AGG_SLOT

    // residual edges (cnt > 64): essentially never taken, kept for correctness
    for (int t = e + 64; t < cnt; t += 16) {
        int sr = esrc[start + t];
        float4 hs4 = hp[(size_t)sr * 4 + q];
        float invs = inv[sr];
        float p = hs4.x * hd4.x + hs4.y * hd4.y + hs4.z * hd4.z + hs4.w * hd4.w;
        p += __shfl_xor(p, 1);
        p += __shfl_xor(p, 2);
        float w = __expf(beta * (p * invd * invs) - shift);
        denom += w;
        acc.x += w * hs4.x;
        acc.y += w * hs4.y;
        acc.z += w * hs4.z;
        acc.w += w * hs4.w;
    }

    // reduce across the 16 edge slots (lane bits 2..5)
#pragma unroll
    for (int off = 4; off <= 32; off <<= 1) {
        denom += __shfl_xor(denom, off);
        acc.x += __shfl_xor(acc.x, off);
        acc.y += __shfl_xor(acc.y, off);
        acc.z += __shfl_xor(acc.z, off);
        acc.w += __shfl_xor(acc.w, off);
    }
    float rd = 1.f / denom;        // denom>0 guaranteed by self-loop
    float4 o = make_float4(acc.x * rd, acc.y * rd, acc.z * rd, acc.w * rd);

    if (!LAST) {
        if (lane < 4) ((float4*)(hout + (size_t)node * HID))[q] = o;
        float ss = o.x * o.x + o.y * o.y + o.z * o.z + o.w * o.w;
        ss += __shfl_xor(ss, 1);
        ss += __shfl_xor(ss, 2);
        if (lane == 0) invout[node] = 1.f / fmaxf(sqrtf(ss), 1e-12f);
    } else {
        // ---- fused classifier: every lane = one class ----
        float h2f[16];
#pragma unroll
        for (int qp = 0; qp < 4; ++qp) {
            int srcl = (lane & ~3) | qp;   // a lane holding quad qp's totals
            h2f[4 * qp + 0] = __shfl(o.x, srcl);
            h2f[4 * qp + 1] = __shfl(o.y, srcl);
            h2f[4 * qp + 2] = __shfl(o.z, srcl);
            h2f[4 * qp + 3] = __shfl(o.w, srcl);
        }
        float logit = b2[lane];
#pragma unroll
        for (int k = 0; k < HID; ++k)
            logit += h2f[k] * W2[k * NCLS + lane];
        float m = logit;
        for (int off = 32; off > 0; off >>= 1) m = fmaxf(m, __shfl_xor(m, off));
        float ex = __expf(logit - m);
        float ssum = ex;
        for (int off = 32; off > 0; off >>= 1) ssum += __shfl_xor(ssum, off);
        out[(size_t)node * NCLS + lane] = (logit - m) - __logf(ssum);
    }
}

// ---------------------------------------------------------------------------
extern "C" void kernel_launch(void* const* d_in, const int* in_sizes, int n_in,
                              void* d_out, int out_size, void* d_ws, size_t ws_size,
                              hipStream_t stream)
{
    const float* x     = (const float*)d_in[0];
    const int*   eidx  = (const int*)d_in[1];
    const float* W1    = (const float*)d_in[2];
    const float* b1    = (const float*)d_in[3];
    const float* W2    = (const float*)d_in[4];
    const float* b2    = (const float*)d_in[5];
    const float* beta1 = (const float*)d_in[6];
    const float* beta2 = (const float*)d_in[7];

    int N = in_sizes[0] / F_IN;       // 100000
    int E = in_sizes[1] / 2;          // 3200000
    const int* src = eidx;
    const int* dst = eidx + E;
    float* out = (float*)d_out;

    int EV    = E + N;                // virtual edges (incl. self-loops)
    int nbuck = (N + 255) / 256;      // 391

    char* wptr = (char*)d_ws;
    auto alloc = [&](size_t bytes) -> char* {
        char* p = wptr;
        wptr += (bytes + 255) / 256 * 256;
        return p;
    };
    float*    h0       = (float*)alloc((size_t)N * HID * 4);
    float*    inv0     = (float*)alloc((size_t)N * 4);
    float*    h1       = (float*)alloc((size_t)N * HID * 4);
    float*    inv1     = (float*)alloc((size_t)N * 4);
    int*      counts   = (int*)alloc((size_t)N * 4);
    int*      rowstart = (int*)alloc((size_t)(N + 1) * 4);
    int*      esrc     = (int*)alloc((size_t)EV * 4);
    unsigned* staged   = (unsigned*)alloc((size_t)EV * 4);
    int*      bucketCount = (int*)alloc((size_t)(nbuck + 2) * 4);  // +doneCnt
    int*      bucketStart = (int*)alloc((size_t)(nbuck + 1) * 4);
    int*      gCursor     = (int*)alloc((size_t)nbuck * 4);
    int*      doneCnt     = bucketCount + nbuck + 1;

    int ebBlocks = (EV + EPB - 1) / EPB;  // 403

    // CSR front: zero counts+done, then fused hist+scan (last block scans)
    hipMemsetAsync(bucketCount, 0, (size_t)(nbuck + 2) * 4, stream);
    histscan_kernel<<<ebBlocks, 256, 0, stream>>>(dst, E, EV, nbuck, ebBlocks,
                                                  bucketCount, doneCnt,
                                                  bucketStart, gCursor);

    // partition + gemm rows [0, rSplit) overlapped in one launch;
    // build_csr + gemm rows [rSplit, N) in the next. CSR blocks come first
    // in dispatch order so the CSR chain isn't delayed.
    int rSplit   = 60000;
    int gcBlocks = 1024;   // 4096 gemm waves alongside partition
    int gdBlocks = 768;    // 3072 gemm waves alongside build_csr
    part_gemm_kernel<<<ebBlocks + gcBlocks, 256, 0, stream>>>(
        src, dst, E, EV, nbuck, gCursor, staged,
        x, W1, b1, h0, inv0, 0, rSplit, ebBlocks, gcBlocks * 4);
    build_gemm_kernel<<<nbuck + gdBlocks, 256, 0, stream>>>(
        staged, bucketStart, counts, rowstart, esrc, N,
        x, W1, b1, h0, inv0, rSplit, N, nbuck, gdBlocks * 4);

    // attention layer 1 (writes h1/inv1), then layer 2 FUSED with classifier
    int aggBlocks = (N + 3) / 4;   // 4 waves (nodes) per 256-thread block
    agg_kernel<0><<<aggBlocks, 256, 0, stream>>>(h0, inv0, esrc, rowstart, counts,
                                                 beta1, h1, inv1,
                                                 (const float*)nullptr,
                                                 (const float*)nullptr,
                                                 (float*)nullptr, N);
    agg_kernel<1><<<aggBlocks, 256, 0, stream>>>(h1, inv1, esrc, rowstart, counts,
                                                 beta2, (float*)nullptr,
                                                 (float*)nullptr,
                                                 W2, b2, out, N);
}